// Round 1
// baseline (20364.174 us; speedup 1.0000x reference)
//
#include <hip/hip_runtime.h>
#include <hip/hip_bf16.h>

typedef unsigned int uint32;
typedef unsigned short u16;

#define BB 128
#define TT 512
#define HE 256      // encoder hidden
#define G3E 768
#define HD 512      // decoder hidden (2H)
#define G3D 1536
#define LL 64
#define NDICT 30
#define EMBD 256

__device__ __forceinline__ float sigm(float v){ return 1.f/(1.f + expf(-v)); }
__device__ __forceinline__ u16 f2bf(float f){
  uint32 u = __float_as_uint(f);
  u = (u + 0x7FFFu + ((u >> 16) & 1u)) >> 16;
  return (u16)u;
}
__device__ __forceinline__ float bf2f(u16 h){ return __uint_as_float(((uint32)h) << 16); }

// ---------- prep: generic transpose  dst[c*R + r] = src[r*C + c] ----------
__global__ __launch_bounds__(256) void k_transpose(const float* __restrict__ src,
                                                   float* __restrict__ dst, int R, int C){
  int idx = blockIdx.x*256 + threadIdx.x;
  if (idx < R*C){
    int r = idx / C, c = idx - r*C;
    dst[(size_t)c*R + r] = src[idx];
  }
}

// ---------- prep: encoder Whh [768][256] -> interleaved [k/4][768][4] ----------
__global__ __launch_bounds__(256) void k_interleave_whh(const float* __restrict__ src,
                                                        float* __restrict__ dst){
  int idx = blockIdx.x*256 + threadIdx.x;      // 768*256
  int j = idx >> 8, k = idx & 255;
  dst[((size_t)(k >> 2)*G3E + j)*4 + (k & 3)] = src[idx];
}

// ---------- encoder: one block per (batch-pair, direction); 512 steps in-kernel ----------
__global__ __launch_bounds__(768) void k_encoder(
    const float* __restrict__ x,
    const float* __restrict__ WihF, const float* __restrict__ WihB,
    const float* __restrict__ W4F,  const float* __restrict__ W4B,
    const float* __restrict__ bihF, const float* __restrict__ bhhF,
    const float* __restrict__ bihB, const float* __restrict__ bhhB,
    u16* __restrict__ enc_out, float* __restrict__ h0out)
{
  const int d  = blockIdx.x & 1;
  const int b0 = (blockIdx.x >> 1) * 2;
  const int j  = threadIdx.x;
  const float*  Wih = d ? WihB : WihF;
  const float4* W4  = (const float4*)(d ? W4B : W4F);
  const float*  bih = d ? bihB : bihF;
  const float*  bhh = d ? bhhB : bhhF;

  __shared__ float wv0[G3E], wv1[G3E], bis[G3E], bhs[G3E];
  __shared__ __align__(16) float h_s[2][HE];
  __shared__ float gh_s[2][G3E];

  wv0[j] = Wih[j*2+0]; wv1[j] = Wih[j*2+1];
  bis[j] = bih[j];     bhs[j] = bhh[j];
  if (j < 2*HE) h_s[j>>8][j&255] = 0.f;

  for (int t = 0; t < TT; ++t){
    const int tt = d ? (TT-1-t) : t;
    __syncthreads();
    float xa0 = x[(size_t)b0*TT*2     + tt*2 + 0];
    float xa1 = x[(size_t)b0*TT*2     + tt*2 + 1];
    float xb0 = x[(size_t)(b0+1)*TT*2 + tt*2 + 0];
    float xb1 = x[(size_t)(b0+1)*TT*2 + tt*2 + 1];

    float acc0 = 0.f, acc1 = 0.f;
    #pragma unroll 8
    for (int kk = 0; kk < HE/4; ++kk){
      float4 w = W4[(size_t)kk*G3E + j];
      float4 p = *(const float4*)&h_s[0][kk*4];
      float4 q = *(const float4*)&h_s[1][kk*4];
      acc0 = fmaf(w.x,p.x, fmaf(w.y,p.y, fmaf(w.z,p.z, fmaf(w.w,p.w, acc0))));
      acc1 = fmaf(w.x,q.x, fmaf(w.y,q.y, fmaf(w.z,q.z, fmaf(w.w,q.w, acc1))));
    }
    gh_s[0][j] = acc0; gh_s[1][j] = acc1;
    __syncthreads();

    if (j < 2*HE){
      const int bb = j >> 8, k = j & 255;
      float X0 = bb ? xb0 : xa0, X1 = bb ? xb1 : xa1;
      float gr = wv0[k]*X0 + wv1[k]*X1 + bis[k] + gh_s[bb][k] + bhs[k];
      float gz = wv0[k+HE]*X0 + wv1[k+HE]*X1 + bis[k+HE] + gh_s[bb][k+HE] + bhs[k+HE];
      float r = sigm(gr), z = sigm(gz);
      float gin = wv0[k+2*HE]*X0 + wv1[k+2*HE]*X1 + bis[k+2*HE];
      float ghn = gh_s[bb][k+2*HE] + bhs[k+2*HE];
      float n = tanhf(gin + r*ghn);
      float hnew = (1.f - z)*n + z*h_s[bb][k];
      h_s[bb][k] = hnew;
      enc_out[((size_t)(b0+bb)*TT + tt)*HD + d*HE + k] = f2bf(hnew);
    }
  }
  __syncthreads();
  if (j < 2*HE){
    const int bb = j >> 8, k = j & 255;
    h0out[(size_t)(b0+bb)*HD + d*HE + k] = h_s[bb][k];
  }
}

// ---------- decoder GRU step (gates + combine fused) ----------
__global__ __launch_bounds__(256) void k_dec_gru(
    const int* __restrict__ tgt, const float* __restrict__ emb,
    const float* __restrict__ WihT, const float* __restrict__ WhhT,
    const float* __restrict__ bih, const float* __restrict__ bhh,
    const float* __restrict__ h_old, float* __restrict__ h_new, int l)
{
  const int bt = blockIdx.x, ht = blockIdx.y;   // grid (8, 32)
  const int tid = threadIdx.x;
  __shared__ float e_s[16][EMBD];
  __shared__ float h_s[16][HD];

  for (int i = 0; i < 16; ++i){
    int f = tid + i*256; int bl = f >> 8, c = f & 255;
    int b = bt*16 + bl;
    int tok = (l == 0) ? 1 : tgt[b*LL + (l-1)];
    e_s[bl][c] = emb[(size_t)tok*EMBD + c];
  }
  for (int i = 0; i < 32; ++i){
    int f = tid + i*256; int bl = f >> 9, c = f & 511;
    h_s[bl][c] = h_old[(size_t)(bt*16 + bl)*HD + c];
  }
  __syncthreads();

  const int bl = tid >> 4, hl = tid & 15;
  const int hk = ht*16 + hl;
  const int b  = bt*16 + bl;
  float air=0.f, aiz=0.f, ain=0.f;
  #pragma unroll 4
  for (int k = 0; k < EMBD; ++k){
    float ev = e_s[bl][k];
    air = fmaf(WihT[(size_t)k*G3D + hk],        ev, air);
    aiz = fmaf(WihT[(size_t)k*G3D + HD + hk],   ev, aiz);
    ain = fmaf(WihT[(size_t)k*G3D + 2*HD + hk], ev, ain);
  }
  float ahr=0.f, ahz=0.f, ahn=0.f;
  #pragma unroll 4
  for (int k = 0; k < HD; ++k){
    float hv = h_s[bl][k];
    ahr = fmaf(WhhT[(size_t)k*G3D + hk],        hv, ahr);
    ahz = fmaf(WhhT[(size_t)k*G3D + HD + hk],   hv, ahz);
    ahn = fmaf(WhhT[(size_t)k*G3D + 2*HD + hk], hv, ahn);
  }
  float r = sigm(air + bih[hk]      + ahr + bhh[hk]);
  float z = sigm(aiz + bih[HD+hk]   + ahz + bhh[HD+hk]);
  float n = tanhf(ain + bih[2*HD+hk] + r*(ahn + bhh[2*HD+hk]));
  float hnew = (1.f - z)*n + z*h_s[bl][hk];
  h_new[(size_t)b*HD + hk] = hnew;
}

// ---------- q = h @ Wq.T + bq ----------
__global__ __launch_bounds__(512) void k_query(
    const float* __restrict__ h, const float* __restrict__ WqT,
    const float* __restrict__ bq, float* __restrict__ q)
{
  const int bt = blockIdx.x, nt = blockIdx.y;   // grid (8, 8)
  const int tid = threadIdx.x;
  __shared__ float h_s[16][HD];
  for (int i = 0; i < 16; ++i){
    int f = tid + i*512; int bl = f >> 9, c = f & 511;
    h_s[bl][c] = h[(size_t)(bt*16+bl)*HD + c];
  }
  __syncthreads();
  const int bl = tid >> 5, nl = tid & 31;
  const int n0 = nt*64 + nl, n1 = n0 + 32;
  float a0 = 0.f, a1 = 0.f;
  #pragma unroll 4
  for (int k = 0; k < HD; ++k){
    float hv = h_s[bl][k];
    a0 = fmaf(WqT[(size_t)k*HD + n0], hv, a0);
    a1 = fmaf(WqT[(size_t)k*HD + n1], hv, a1);
  }
  const int b = bt*16 + bl;
  q[(size_t)b*HD + n0] = a0 + bq[n0];
  q[(size_t)b*HD + n1] = a1 + bq[n1];
}

// ---------- attention: single pass over enc_out, online softmax + ctx ----------
__global__ __launch_bounds__(256) void k_attn(
    const float* __restrict__ q, const u16* __restrict__ enc,
    float* __restrict__ ctx, float* __restrict__ attn_out, int l)
{
  const int b = blockIdx.x, tid = threadIdx.x;
  __shared__ float q_s[HD];
  __shared__ float s_s[TT];
  __shared__ __align__(16) u16 e_s[16][HD];
  __shared__ float p_s[16];

  q_s[tid]     = q[(size_t)b*HD + tid];
  q_s[tid+256] = q[(size_t)b*HD + tid + 256];

  float m = -1e30f, Z = 0.f, c0 = 0.f, c1 = 0.f;
  for (int cc = 0; cc < TT/16; ++cc){
    const int t0 = cc*16;
    const uint4* src = (const uint4*)(enc + ((size_t)b*TT + t0)*HD);
    uint4* dstv = (uint4*)&e_s[0][0];
    #pragma unroll
    for (int i = 0; i < 4; ++i) dstv[tid + i*256] = src[tid + i*256];
    __syncthreads();

    // 16 scores, one per 16-lane group
    const int g = tid >> 4, li = tid & 15;
    float part = 0.f;
    #pragma unroll 8
    for (int i = 0; i < 32; ++i){
      int c = li + i*16;
      part = fmaf(q_s[c], bf2f(e_s[g][c]), part);
    }
    part += __shfl_xor(part, 1);
    part += __shfl_xor(part, 2);
    part += __shfl_xor(part, 4);
    part += __shfl_xor(part, 8);
    if (li == 0) s_s[t0 + g] = part;
    __syncthreads();

    float mc = m;
    #pragma unroll
    for (int i = 0; i < 16; ++i) mc = fmaxf(mc, s_s[t0+i]);
    float alpha = expf(m - mc);
    if (tid < 16) p_s[tid] = expf(s_s[t0+tid] - mc);
    m = mc;
    __syncthreads();

    float zs = 0.f, a0 = 0.f, a1 = 0.f;
    #pragma unroll
    for (int i = 0; i < 16; ++i){
      float p = p_s[i];
      zs += p;
      a0 = fmaf(p, bf2f(e_s[i][tid]),     a0);
      a1 = fmaf(p, bf2f(e_s[i][tid+256]), a1);
    }
    Z  = Z*alpha  + zs;
    c0 = c0*alpha + a0;
    c1 = c1*alpha + a1;
    __syncthreads();
  }
  const float invZ = 1.f / Z;
  #pragma unroll
  for (int i = 0; i < 2; ++i){
    int t = tid + i*256;
    attn_out[((size_t)b*TT + t)*LL + l] = expf(s_s[t] - m)*invZ;
  }
  ctx[(size_t)b*HD + tid]       = c0*invZ;
  ctx[(size_t)b*HD + tid + 256] = c1*invZ;
}

// ---------- o = [h|ctx] @ Wc.T + bc ----------
__global__ __launch_bounds__(256) void k_outc(
    const float* __restrict__ h, const float* __restrict__ ctxv,
    const float* __restrict__ WcT, const float* __restrict__ bc,
    float* __restrict__ o)
{
  const int bt = blockIdx.x, nt = blockIdx.y;   // grid (8, 16)
  const int tid = threadIdx.x;
  __shared__ float in_s[16][HD];
  const int bl = tid >> 4, nl = tid & 15;
  const int n = nt*16 + nl;
  float acc = 0.f;

  for (int i = 0; i < 32; ++i){
    int f = tid + i*256; int b_ = f >> 9, c = f & 511;
    in_s[b_][c] = h[(size_t)(bt*16+b_)*HD + c];
  }
  __syncthreads();
  #pragma unroll 4
  for (int k = 0; k < HD; ++k)
    acc = fmaf(WcT[(size_t)k*256 + n], in_s[bl][k], acc);
  __syncthreads();
  for (int i = 0; i < 32; ++i){
    int f = tid + i*256; int b_ = f >> 9, c = f & 511;
    in_s[b_][c] = ctxv[(size_t)(bt*16+b_)*HD + c];
  }
  __syncthreads();
  #pragma unroll 4
  for (int k = 0; k < HD; ++k)
    acc = fmaf(WcT[(size_t)(k+HD)*256 + n], in_s[bl][k], acc);

  const int b = bt*16 + bl;
  o[(size_t)b*256 + n] = acc + bc[n];
}

// ---------- logits = o @ Wf.T + bf ----------
__global__ __launch_bounds__(512) void k_fc(
    const float* __restrict__ o, const float* __restrict__ Wf,
    const float* __restrict__ bf_, float* __restrict__ out, int l)
{
  const int bt = blockIdx.x, tid = threadIdx.x;   // grid 8
  __shared__ float o_s[16][256];
  for (int i = 0; i < 8; ++i){
    int f = tid + i*512; int b_ = f >> 8, c = f & 255;
    o_s[b_][c] = o[(size_t)(bt*16+b_)*256 + c];
  }
  __syncthreads();
  if (tid < 480){
    int bl = tid / 30, dd = tid - bl*30;
    float acc = bf_[dd];
    #pragma unroll 4
    for (int k = 0; k < 256; ++k) acc = fmaf(Wf[dd*256+k], o_s[bl][k], acc);
    out[(size_t)(bt*16+bl)*(LL*NDICT) + l*NDICT + dd] = acc;
  }
}

__global__ __launch_bounds__(256) void k_copy(const float* __restrict__ src,
                                              float* __restrict__ dst, int n){
  int i = blockIdx.x*256 + threadIdx.x;
  if (i < n) dst[i] = src[i];
}

extern "C" void kernel_launch(void* const* d_in, const int* in_sizes, int n_in,
                              void* d_out, int out_size, void* d_ws, size_t ws_size,
                              hipStream_t stream)
{
  const float* x     = (const float*)d_in[0];
  const int*   tgt   = (const int*)  d_in[1];
  const float* eWihF = (const float*)d_in[2];
  const float* eWhhF = (const float*)d_in[3];
  const float* ebihF = (const float*)d_in[4];
  const float* ebhhF = (const float*)d_in[5];
  const float* eWihB = (const float*)d_in[6];
  const float* eWhhB = (const float*)d_in[7];
  const float* ebihB = (const float*)d_in[8];
  const float* ebhhB = (const float*)d_in[9];
  const float* emb   = (const float*)d_in[10];
  const float* dWih  = (const float*)d_in[11];
  const float* dWhh  = (const float*)d_in[12];
  const float* dbih  = (const float*)d_in[13];
  const float* dbhh  = (const float*)d_in[14];
  const float* Wq    = (const float*)d_in[15];
  const float* bq    = (const float*)d_in[16];
  const float* Wc    = (const float*)d_in[17];
  const float* bc    = (const float*)d_in[18];
  const float* Wf    = (const float*)d_in[19];
  const float* bfv   = (const float*)d_in[20];

  float* ws = (float*)d_ws;
  size_t off = 0;
  float* W4F   = ws + off; off += (size_t)G3E*HE;
  float* W4B   = ws + off; off += (size_t)G3E*HE;
  float* WihTd = ws + off; off += (size_t)EMBD*G3D;
  float* WhhTd = ws + off; off += (size_t)HD*G3D;
  float* WqT   = ws + off; off += (size_t)HD*HD;
  float* WcT   = ws + off; off += (size_t)1024*256;
  float* qbuf  = ws + off; off += (size_t)BB*HD;
  float* ctxb  = ws + off; off += (size_t)BB*HD;
  float* obuf  = ws + off; off += (size_t)BB*256;
  float* hb0   = ws + off; off += (size_t)BB*HD;
  float* hb1   = ws + off; off += (size_t)BB*HD;
  u16*   encb  = (u16*)(ws + off);   // [128][512][512] bf16

  float* out     = (float*)d_out;
  float* out_vec = out;                              // [128][64][30]
  float* out_hT  = out + (size_t)BB*LL*NDICT;        // [1][128][512]
  float* out_att = out_hT + (size_t)BB*HD;           // [128][512][64]

  // prep
  k_interleave_whh<<<G3E, 256, 0, stream>>>(eWhhF, W4F);
  k_interleave_whh<<<G3E, 256, 0, stream>>>(eWhhB, W4B);
  k_transpose<<<(G3D*EMBD+255)/256, 256, 0, stream>>>(dWih, WihTd, G3D, EMBD);
  k_transpose<<<(G3D*HD+255)/256,   256, 0, stream>>>(dWhh, WhhTd, G3D, HD);
  k_transpose<<<(HD*HD+255)/256,    256, 0, stream>>>(Wq,   WqT,   HD, HD);
  k_transpose<<<(256*1024+255)/256, 256, 0, stream>>>(Wc,   WcT,   256, 1024);

  // encoder (both directions, persistent over 512 steps)
  k_encoder<<<BB, G3E, 0, stream>>>(x, eWihF, eWihB, W4F, W4B,
                                    ebihF, ebhhF, ebihB, ebhhB, encb, hb0);

  // decoder: 64 teacher-forced steps
  for (int l = 0; l < LL; ++l){
    float* hold = (l & 1) ? hb1 : hb0;
    float* hnew = (l & 1) ? hb0 : hb1;
    k_dec_gru<<<dim3(8,32), 256, 0, stream>>>(tgt, emb, WihTd, WhhTd, dbih, dbhh,
                                              hold, hnew, l);
    k_query<<<dim3(8,8), 512, 0, stream>>>(hnew, WqT, bq, qbuf);
    k_attn<<<BB, 256, 0, stream>>>(qbuf, encb, ctxb, out_att, l);
    k_outc<<<dim3(8,16), 256, 0, stream>>>(hnew, ctxb, WcT, bc, obuf);
    k_fc<<<8, 512, 0, stream>>>(obuf, Wf, bfv, out_vec, l);
  }
  k_copy<<<(BB*HD+255)/256, 256, 0, stream>>>(hb0, out_hT, BB*HD);
}

// Round 2
// 4360.213 us; speedup vs baseline: 4.6705x; 4.6705x over previous
//
#include <hip/hip_runtime.h>
#include <hip/hip_bf16.h>

typedef unsigned int u32;
typedef unsigned short u16;

#define BB 128
#define TT 512
#define HE 256      // encoder hidden
#define G3E 768
#define HD 512      // decoder hidden (2H)
#define G3D 1536
#define LL 64
#define NDICT 30
#define EMBD 256

__device__ __forceinline__ float sigm(float v){ return 1.f/(1.f + expf(-v)); }
__device__ __forceinline__ u16 f2bf(float f){
  u32 u = __float_as_uint(f);
  u = (u + 0x7FFFu + ((u >> 16) & 1u)) >> 16;
  return (u16)u;
}
__device__ __forceinline__ float bf2f(u16 h){ return __uint_as_float(((u32)h) << 16); }

__device__ __forceinline__ void unp8(uint4 v, float* d){
  d[0]=__uint_as_float((v.x&0xffffu)<<16); d[1]=__uint_as_float(v.x&0xffff0000u);
  d[2]=__uint_as_float((v.y&0xffffu)<<16); d[3]=__uint_as_float(v.y&0xffff0000u);
  d[4]=__uint_as_float((v.z&0xffffu)<<16); d[5]=__uint_as_float(v.z&0xffff0000u);
  d[6]=__uint_as_float((v.w&0xffffu)<<16); d[7]=__uint_as_float(v.w&0xffff0000u);
}

__device__ __forceinline__ ushort4 pk4(float a, float b, float c, float d){
  ushort4 r; r.x=f2bf(a); r.y=f2bf(b); r.z=f2bf(c); r.w=f2bf(d); return r;
}

// 16-FMA inner step for the 64x64-tile GEMMs (A_s/B_s are [32][68] k-major)
#define INNER16(Q0,Q1)                                              \
  _Pragma("unroll 8")                                               \
  for (int k = 0; k < 32; ++k){                                     \
    float4 a4 = *(const float4*)&A_s[k*68 + (Q0)*4];                \
    float4 b4 = *(const float4*)&B_s[k*68 + (Q1)*4];                \
    acc[0] =fmaf(a4.x,b4.x,acc[0]);  acc[1] =fmaf(a4.x,b4.y,acc[1]); \
    acc[2] =fmaf(a4.x,b4.z,acc[2]);  acc[3] =fmaf(a4.x,b4.w,acc[3]); \
    acc[4] =fmaf(a4.y,b4.x,acc[4]);  acc[5] =fmaf(a4.y,b4.y,acc[5]); \
    acc[6] =fmaf(a4.y,b4.z,acc[6]);  acc[7] =fmaf(a4.y,b4.w,acc[7]); \
    acc[8] =fmaf(a4.z,b4.x,acc[8]);  acc[9] =fmaf(a4.z,b4.y,acc[9]); \
    acc[10]=fmaf(a4.z,b4.z,acc[10]); acc[11]=fmaf(a4.z,b4.w,acc[11]);\
    acc[12]=fmaf(a4.w,b4.x,acc[12]); acc[13]=fmaf(a4.w,b4.y,acc[13]);\
    acc[14]=fmaf(a4.w,b4.z,acc[14]); acc[15]=fmaf(a4.w,b4.w,acc[15]);\
  }

// ---------- prep: generic transpose  dst[c*R + r] = src[r*C + c] ----------
__global__ __launch_bounds__(256) void k_transpose(const float* __restrict__ src,
                                                   float* __restrict__ dst, int R, int C){
  int idx = blockIdx.x*256 + threadIdx.x;
  if (idx < R*C){
    int r = idx / C, c = idx - r*C;
    dst[(size_t)c*R + r] = src[idx];
  }
}

// ---------- prep: encoder Whh [768][256] -> interleaved [k/4][768][4] ----------
__global__ __launch_bounds__(256) void k_interleave_whh(const float* __restrict__ src,
                                                        float* __restrict__ dst){
  int idx = blockIdx.x*256 + threadIdx.x;      // 768*256
  int j = idx >> 8, k = idx & 255;
  dst[((size_t)(k >> 2)*G3E + j)*4 + (k & 3)] = src[idx];
}

// ---------- prep: decoder Whh [1536][512] -> [ct 32][kq 128][g 3][c 16][kk 4] ----------
__global__ __launch_bounds__(256) void k_prep_whhd(const float* __restrict__ src,
                                                   float* __restrict__ dst){
  int idx = blockIdx.x*256 + threadIdx.x;      // 1536*512
  int G = idx >> 9, K = idx & 511;
  int g = G >> 9;
  int rem = G & 511;
  int ct = rem >> 4, c = rem & 15;
  int kq = K >> 2, kk = K & 3;
  dst[(size_t)ct*24576 + kq*192 + g*64 + c*4 + kk] = src[idx];
}

// ---------- prep: gi[v][g] = emb[v]@dWih[g] + bih[g] ----------
__global__ __launch_bounds__(256) void k_gi_tab(const float* __restrict__ emb,
                                                const float* __restrict__ Wih,
                                                const float* __restrict__ bih,
                                                float* __restrict__ gi){
  int v = blockIdx.x, gy = blockIdx.y;   // grid (30, 6)
  int g = gy*256 + threadIdx.x;
  __shared__ float e_s[EMBD];
  if (threadIdx.x < EMBD) e_s[threadIdx.x] = emb[(size_t)v*EMBD + threadIdx.x];
  __syncthreads();
  const float4* w4 = (const float4*)(Wih + (size_t)g*EMBD);
  float acc = 0.f;
  #pragma unroll 8
  for (int k = 0; k < EMBD/4; ++k){
    float4 w = w4[k];
    float4 h = *(const float4*)&e_s[k*4];
    acc = fmaf(w.x,h.x,fmaf(w.y,h.y,fmaf(w.z,h.z,fmaf(w.w,h.w,acc))));
  }
  gi[(size_t)v*G3D + g] = acc + bih[g];
}

// ---------- encoder: one block per (batch-pair, direction); 512 steps in-kernel ----------
__global__ __launch_bounds__(768) void k_encoder(
    const float* __restrict__ x,
    const float* __restrict__ WihF, const float* __restrict__ WihB,
    const float* __restrict__ W4F,  const float* __restrict__ W4B,
    const float* __restrict__ bihF, const float* __restrict__ bhhF,
    const float* __restrict__ bihB, const float* __restrict__ bhhB,
    u16* __restrict__ enc_out, float* __restrict__ h0out)
{
  const int d  = blockIdx.x & 1;
  const int b0 = (blockIdx.x >> 1) * 2;
  const int j  = threadIdx.x;
  const float*  Wih = d ? WihB : WihF;
  const float4* W4  = (const float4*)(d ? W4B : W4F);
  const float*  bih = d ? bihB : bihF;
  const float*  bhh = d ? bhhB : bhhF;

  __shared__ float wv0[G3E], wv1[G3E], bis[G3E], bhs[G3E];
  __shared__ __align__(16) float h_s[2][HE];
  __shared__ float gh_s[2][G3E];

  wv0[j] = Wih[j*2+0]; wv1[j] = Wih[j*2+1];
  bis[j] = bih[j];     bhs[j] = bhh[j];
  if (j < 2*HE) h_s[j>>8][j&255] = 0.f;

  for (int t = 0; t < TT; ++t){
    const int tt = d ? (TT-1-t) : t;
    __syncthreads();
    float xa0 = x[(size_t)b0*TT*2     + tt*2 + 0];
    float xa1 = x[(size_t)b0*TT*2     + tt*2 + 1];
    float xb0 = x[(size_t)(b0+1)*TT*2 + tt*2 + 0];
    float xb1 = x[(size_t)(b0+1)*TT*2 + tt*2 + 1];

    float acc0 = 0.f, acc1 = 0.f;
    #pragma unroll 8
    for (int kk = 0; kk < HE/4; ++kk){
      float4 w = W4[(size_t)kk*G3E + j];
      float4 p = *(const float4*)&h_s[0][kk*4];
      float4 q = *(const float4*)&h_s[1][kk*4];
      acc0 = fmaf(w.x,p.x, fmaf(w.y,p.y, fmaf(w.z,p.z, fmaf(w.w,p.w, acc0))));
      acc1 = fmaf(w.x,q.x, fmaf(w.y,q.y, fmaf(w.z,q.z, fmaf(w.w,q.w, acc1))));
    }
    gh_s[0][j] = acc0; gh_s[1][j] = acc1;
    __syncthreads();

    if (j < 2*HE){
      const int bb = j >> 8, k = j & 255;
      float X0 = bb ? xb0 : xa0, X1 = bb ? xb1 : xa1;
      float gr = wv0[k]*X0 + wv1[k]*X1 + bis[k] + gh_s[bb][k] + bhs[k];
      float gz = wv0[k+HE]*X0 + wv1[k+HE]*X1 + bis[k+HE] + gh_s[bb][k+HE] + bhs[k+HE];
      float r = sigm(gr), z = sigm(gz);
      float gin = wv0[k+2*HE]*X0 + wv1[k+2*HE]*X1 + bis[k+2*HE];
      float ghn = gh_s[bb][k+2*HE] + bhs[k+2*HE];
      float n = tanhf(gin + r*ghn);
      float hnew = (1.f - z)*n + z*h_s[bb][k];
      h_s[bb][k] = hnew;
      enc_out[((size_t)(b0+bb)*TT + tt)*HD + d*HE + k] = f2bf(hnew);
    }
  }
  __syncthreads();
  if (j < 2*HE){
    const int bb = j >> 8, k = j & 255;
    h0out[(size_t)(b0+bb)*HD + d*HE + k] = h_s[bb][k];
  }
}

// ---------- decoder recurrence: one step, gh = h@Whh^T, gates, h_new ----------
// grid (256): bt = blk&7 (16 b each), ct = blk>>3 (16 h-cols each); 256 threads = 16b x 16c
__global__ __launch_bounds__(256) void k_hstep(
    const int* __restrict__ tgt, const float* __restrict__ gi_tab,
    const float* __restrict__ whh_i, const float* __restrict__ bhh,
    const float* __restrict__ hprev, float* __restrict__ hout, int l)
{
  const int bt = blockIdx.x & 7, ct = blockIdx.x >> 3;
  const int tid = threadIdx.x;
  const int b = tid & 15, c = tid >> 4;
  __shared__ float h_s[16*516];
  __shared__ float wtile[32*192];
  __shared__ int tok_s[16];

  {
    const int bs = tid >> 4, seg = tid & 15;
    const float4* src = (const float4*)(hprev + (size_t)(bt*16+bs)*HD + seg*32);
    float4* dst = (float4*)&h_s[bs*516 + seg*32];
    #pragma unroll
    for (int r = 0; r < 8; ++r) dst[r] = src[r];
  }
  if (tid < 16) tok_s[tid] = (l == 0) ? 1 : tgt[(size_t)(bt*16+tid)*LL + (l-1)];

  float gr = 0.f, gz = 0.f, gn = 0.f;
  const float* wbase = whh_i + (size_t)ct*24576;
  for (int kc = 0; kc < 4; ++kc){
    __syncthreads();
    {
      const float4* src = (const float4*)(wbase + kc*6144);
      float4* dst = (float4*)wtile;
      #pragma unroll
      for (int i = 0; i < 6; ++i) dst[tid + i*256] = src[tid + i*256];
    }
    __syncthreads();
    #pragma unroll 8
    for (int kq = 0; kq < 32; ++kq){
      float4 h4 = *(const float4*)&h_s[b*516 + kc*128 + kq*4];
      float4 w0 = *(const float4*)&wtile[kq*192 +       c*4];
      float4 w1 = *(const float4*)&wtile[kq*192 + 64  + c*4];
      float4 w2 = *(const float4*)&wtile[kq*192 + 128 + c*4];
      gr = fmaf(w0.x,h4.x,fmaf(w0.y,h4.y,fmaf(w0.z,h4.z,fmaf(w0.w,h4.w,gr))));
      gz = fmaf(w1.x,h4.x,fmaf(w1.y,h4.y,fmaf(w1.z,h4.z,fmaf(w1.w,h4.w,gz))));
      gn = fmaf(w2.x,h4.x,fmaf(w2.y,h4.y,fmaf(w2.z,h4.z,fmaf(w2.w,h4.w,gn))));
    }
  }
  const int C = ct*16 + c;
  const int tok = tok_s[b];
  float gir = gi_tab[(size_t)tok*G3D + C];
  float giz = gi_tab[(size_t)tok*G3D + HD + C];
  float gin = gi_tab[(size_t)tok*G3D + 2*HD + C];
  float r = sigm(gir + gr + bhh[C]);
  float z = sigm(giz + gz + bhh[HD + C]);
  float n = tanhf(gin + r*(gn + bhh[2*HD + C]));
  float hp = h_s[b*516 + C];
  hout[(size_t)(bt*16+b)*HD + C] = (1.f - z)*n + z*hp;
}

// ---------- Q = Hall @ WqT + bq -> bf16 ; grid (128 rt, 8 nt) ----------
__global__ __launch_bounds__(256) void k_query(const float* __restrict__ Hall,
                                               const float* __restrict__ WqT,
                                               const float* __restrict__ bq,
                                               u16* __restrict__ Qbf){
  const int rt = blockIdx.x, nt = blockIdx.y;
  const int tid = threadIdx.x;
  __shared__ float A_s[32*68];
  __shared__ float B_s[32*68];
  const int rq = tid >> 4, nq = tid & 15;
  const int i = tid >> 2, jj = tid & 3;
  const int i2 = tid >> 3, jj2 = tid & 7;
  float acc[16] = {};
  for (int kc = 0; kc < 16; ++kc){
    __syncthreads();
    {
      const float* src = Hall + (size_t)(rt*64 + i)*HD + kc*32 + jj*8;
      float4 v0 = *(const float4*)src, v1 = *(const float4*)(src+4);
      A_s[(jj*8+0)*68+i]=v0.x; A_s[(jj*8+1)*68+i]=v0.y;
      A_s[(jj*8+2)*68+i]=v0.z; A_s[(jj*8+3)*68+i]=v0.w;
      A_s[(jj*8+4)*68+i]=v1.x; A_s[(jj*8+5)*68+i]=v1.y;
      A_s[(jj*8+6)*68+i]=v1.z; A_s[(jj*8+7)*68+i]=v1.w;
    }
    {
      const float* src = WqT + (size_t)(kc*32 + i2)*HD + nt*64 + jj2*8;
      *(float4*)&B_s[i2*68 + jj2*8]     = *(const float4*)src;
      *(float4*)&B_s[i2*68 + jj2*8 + 4] = *(const float4*)(src+4);
    }
    __syncthreads();
    INNER16(rq, nq)
  }
  const int n0 = nt*64 + nq*4;
  float4 bv = *(const float4*)&bq[n0];
  #pragma unroll
  for (int r = 0; r < 4; ++r){
    u16* dst = Qbf + (size_t)(rt*64 + rq*4 + r)*HD + n0;
    *(ushort4*)dst = pk4(acc[r*4+0]+bv.x, acc[r*4+1]+bv.y,
                         acc[r*4+2]+bv.z, acc[r*4+3]+bv.w);
  }
}

// ---------- S[b][l][t] = Q[b,l,:] . enc[b,t,:] ; grid (128 b, 8 tt) ----------
__global__ __launch_bounds__(256) void k_scores(const u16* __restrict__ Qbf,
                                                const u16* __restrict__ enc,
                                                float* __restrict__ Sbuf){
  const int bI = blockIdx.x, tt = blockIdx.y;
  const int tid = threadIdx.x;
  __shared__ float A_s[32*68];
  __shared__ float B_s[32*68];
  const int lq = tid >> 4, tq = tid & 15;
  const int i = tid >> 2, jj = tid & 3;
  float acc[16] = {};
  for (int kc = 0; kc < 16; ++kc){
    __syncthreads();
    float tmp[8];
    {
      uint4 va = *(const uint4*)(Qbf + ((size_t)i*BB + bI)*HD + kc*32 + jj*8);
      unp8(va, tmp);
      #pragma unroll
      for (int m = 0; m < 8; ++m) A_s[(jj*8+m)*68 + i] = tmp[m];
    }
    {
      uint4 vb = *(const uint4*)(enc + ((size_t)bI*TT + tt*64 + i)*HD + kc*32 + jj*8);
      unp8(vb, tmp);
      #pragma unroll
      for (int m = 0; m < 8; ++m) B_s[(jj*8+m)*68 + i] = tmp[m];
    }
    __syncthreads();
    INNER16(lq, tq)
  }
  #pragma unroll
  for (int r = 0; r < 4; ++r){
    float4 o = make_float4(acc[r*4+0],acc[r*4+1],acc[r*4+2],acc[r*4+3]);
    *(float4*)&Sbuf[((size_t)bI*LL + lq*4+r)*TT + tt*64 + tq*4] = o;
  }
}

// ---------- row softmax over t: P bf16 ; grid 8192 x 64 ----------
__global__ __launch_bounds__(64) void k_softmax(const float* __restrict__ Sbuf,
                                                u16* __restrict__ Pbf){
  const int row = blockIdx.x;
  const int lane = threadIdx.x;
  const float* s = Sbuf + (size_t)row*TT;
  float v[8]; float m = -1e30f;
  #pragma unroll
  for (int i = 0; i < 8; ++i){ v[i] = s[lane + i*64]; m = fmaxf(m, v[i]); }
  #pragma unroll
  for (int o = 32; o; o >>= 1) m = fmaxf(m, __shfl_xor(m, o));
  float Z = 0.f;
  #pragma unroll
  for (int i = 0; i < 8; ++i){ v[i] = expf(v[i] - m); Z += v[i]; }
  #pragma unroll
  for (int o = 32; o; o >>= 1) Z += __shfl_xor(Z, o);
  float inv = 1.f / Z;
  u16* p = Pbf + (size_t)row*TT;
  #pragma unroll
  for (int i = 0; i < 8; ++i) p[lane + i*64] = f2bf(v[i]*inv);
}

// ---------- attn[b][t][l] = f32(P[b][l][t]) ; grid (128 b, 8 tt) ----------
__global__ __launch_bounds__(256) void k_attn_tr(const u16* __restrict__ Pbf,
                                                 float* __restrict__ att){
  const int bI = blockIdx.x, tt = blockIdx.y;
  const int tid = threadIdx.x;
  __shared__ u16 tile[64][72];
  {
    const int i = tid >> 2, jj = tid & 3;
    #pragma unroll
    for (int rep = 0; rep < 2; ++rep){
      int ch = jj + rep*4;
      uint4 v = *(const uint4*)(Pbf + ((size_t)bI*LL + i)*TT + tt*64 + ch*8);
      *(uint4*)&tile[i][ch*8] = v;
    }
  }
  __syncthreads();
  const int t = tid >> 2, jl = tid & 3;
  #pragma unroll
  for (int rep = 0; rep < 4; ++rep){
    int l0 = jl*16 + rep*4;
    float4 o;
    o.x = bf2f(tile[l0+0][t]); o.y = bf2f(tile[l0+1][t]);
    o.z = bf2f(tile[l0+2][t]); o.w = bf2f(tile[l0+3][t]);
    *(float4*)&att[((size_t)bI*TT + tt*64 + t)*LL + l0] = o;
  }
}

// ---------- ctx[l*128+b][n] = P[b,l,:] @ enc[b,:,n] -> bf16 ; grid (128 b, 8 nt) ----------
__global__ __launch_bounds__(256) void k_ctx(const u16* __restrict__ Pbf,
                                             const u16* __restrict__ enc,
                                             u16* __restrict__ ctxb){
  const int bI = blockIdx.x, nt = blockIdx.y;
  const int tid = threadIdx.x;
  __shared__ float A_s[32*68];
  __shared__ float B_s[32*68];
  const int lq = tid >> 4, nq = tid & 15;
  const int i = tid >> 2, jj = tid & 3;
  const int i2 = tid >> 3, jj2 = tid & 7;
  float acc[16] = {};
  for (int tc = 0; tc < 16; ++tc){
    __syncthreads();
    {
      float tmp[8];
      uint4 va = *(const uint4*)(Pbf + ((size_t)bI*LL + i)*TT + tc*32 + jj*8);
      unp8(va, tmp);
      #pragma unroll
      for (int m = 0; m < 8; ++m) A_s[(jj*8+m)*68 + i] = tmp[m];
    }
    {
      float tmp[8];
      uint4 vb = *(const uint4*)(enc + ((size_t)bI*TT + tc*32 + i2)*HD + nt*64 + jj2*8);
      unp8(vb, tmp);
      *(float4*)&B_s[i2*68 + jj2*8]     = make_float4(tmp[0],tmp[1],tmp[2],tmp[3]);
      *(float4*)&B_s[i2*68 + jj2*8 + 4] = make_float4(tmp[4],tmp[5],tmp[6],tmp[7]);
    }
    __syncthreads();
    INNER16(lq, nq)
  }
  const int n0 = nt*64 + nq*4;
  #pragma unroll
  for (int r = 0; r < 4; ++r){
    int ll = lq*4 + r;
    u16* dst = ctxb + ((size_t)ll*BB + bI)*HD + n0;
    *(ushort4*)dst = pk4(acc[r*4+0], acc[r*4+1], acc[r*4+2], acc[r*4+3]);
  }
}

// ---------- o = [Hall|ctx] @ WcT + bc ; grid (128 rt, 4 nt) ----------
__global__ __launch_bounds__(256) void k_outc(const float* __restrict__ Hall,
                                              const u16* __restrict__ ctxb,
                                              const float* __restrict__ WcT,
                                              const float* __restrict__ bc,
                                              float* __restrict__ obuf){
  const int rt = blockIdx.x, nt = blockIdx.y;
  const int tid = threadIdx.x;
  __shared__ float A_s[32*68];
  __shared__ float B_s[32*68];
  const int rq = tid >> 4, nq = tid & 15;
  const int i = tid >> 2, jj = tid & 3;
  const int i2 = tid >> 3, jj2 = tid & 7;
  float acc[16] = {};
  for (int kc = 0; kc < 32; ++kc){
    __syncthreads();
    if (kc < 16){
      const float* src = Hall + (size_t)(rt*64 + i)*HD + kc*32 + jj*8;
      float4 v0 = *(const float4*)src, v1 = *(const float4*)(src+4);
      A_s[(jj*8+0)*68+i]=v0.x; A_s[(jj*8+1)*68+i]=v0.y;
      A_s[(jj*8+2)*68+i]=v0.z; A_s[(jj*8+3)*68+i]=v0.w;
      A_s[(jj*8+4)*68+i]=v1.x; A_s[(jj*8+5)*68+i]=v1.y;
      A_s[(jj*8+6)*68+i]=v1.z; A_s[(jj*8+7)*68+i]=v1.w;
    } else {
      float tmp[8];
      uint4 v = *(const uint4*)(ctxb + (size_t)(rt*64 + i)*HD + (kc-16)*32 + jj*8);
      unp8(v, tmp);
      #pragma unroll
      for (int m = 0; m < 8; ++m) A_s[(jj*8+m)*68 + i] = tmp[m];
    }
    {
      const float* src = WcT + (size_t)(kc*32 + i2)*256 + nt*64 + jj2*8;
      *(float4*)&B_s[i2*68 + jj2*8]     = *(const float4*)src;
      *(float4*)&B_s[i2*68 + jj2*8 + 4] = *(const float4*)(src+4);
    }
    __syncthreads();
    INNER16(rq, nq)
  }
  const int n0 = nt*64 + nq*4;
  float4 bv = *(const float4*)&bc[n0];
  #pragma unroll
  for (int r = 0; r < 4; ++r){
    float4 o = make_float4(acc[r*4+0]+bv.x, acc[r*4+1]+bv.y,
                           acc[r*4+2]+bv.z, acc[r*4+3]+bv.w);
    *(float4*)&obuf[(size_t)(rt*64 + rq*4 + r)*256 + n0] = o;
  }
}

// ---------- logits = o @ Wf^T + bf ; grid 128 ----------
__global__ __launch_bounds__(256) void k_fc(const float* __restrict__ obuf,
                                            const float* __restrict__ Wf,
                                            const float* __restrict__ bfv,
                                            float* __restrict__ out_vec){
  const int rt = blockIdx.x;
  const int tid = threadIdx.x;
  __shared__ float w_s[30*260];
  for (int rr = 0; rr < 30; ++rr) w_s[rr*260 + tid] = Wf[(size_t)rr*256 + tid];
  __syncthreads();
  const int rl = tid >> 2, dq = tid & 3;
  const int r = rt*64 + rl;
  float acc[8] = {};
  for (int k = 0; k < 256; k += 4){
    float4 o4 = *(const float4*)&obuf[(size_t)r*256 + k];
    #pragma unroll
    for (int jq = 0; jq < 8; ++jq){
      int d = dq*8 + jq;
      if (d < 30){
        float4 w4 = *(const float4*)&w_s[d*260 + k];
        acc[jq] = fmaf(o4.x,w4.x,fmaf(o4.y,w4.y,fmaf(o4.z,w4.z,fmaf(o4.w,w4.w,acc[jq]))));
      }
    }
  }
  const int b = r & 127, l = r >> 7;
  #pragma unroll
  for (int jq = 0; jq < 8; ++jq){
    int d = dq*8 + jq;
    if (d < 30) out_vec[((size_t)b*LL + l)*NDICT + d] = acc[jq] + bfv[d];
  }
}

__global__ __launch_bounds__(256) void k_copy(const float* __restrict__ src,
                                              float* __restrict__ dst, int n){
  int i = blockIdx.x*256 + threadIdx.x;
  if (i < n) dst[i] = src[i];
}

extern "C" void kernel_launch(void* const* d_in, const int* in_sizes, int n_in,
                              void* d_out, int out_size, void* d_ws, size_t ws_size,
                              hipStream_t stream)
{
  const float* x     = (const float*)d_in[0];
  const int*   tgt   = (const int*)  d_in[1];
  const float* eWihF = (const float*)d_in[2];
  const float* eWhhF = (const float*)d_in[3];
  const float* ebihF = (const float*)d_in[4];
  const float* ebhhF = (const float*)d_in[5];
  const float* eWihB = (const float*)d_in[6];
  const float* eWhhB = (const float*)d_in[7];
  const float* ebihB = (const float*)d_in[8];
  const float* ebhhB = (const float*)d_in[9];
  const float* emb   = (const float*)d_in[10];
  const float* dWih  = (const float*)d_in[11];
  const float* dWhh  = (const float*)d_in[12];
  const float* dbih  = (const float*)d_in[13];
  const float* dbhh  = (const float*)d_in[14];
  const float* Wq    = (const float*)d_in[15];
  const float* bq    = (const float*)d_in[16];
  const float* Wc    = (const float*)d_in[17];
  const float* bc    = (const float*)d_in[18];
  const float* Wf    = (const float*)d_in[19];
  const float* bfv   = (const float*)d_in[20];

  char* w = (char*)d_ws;
  float* W4F   = (float*)w; w += 786432;
  float* W4B   = (float*)w; w += 786432;
  float* whh_i = (float*)w; w += 3145728;
  float* WqT   = (float*)w; w += 1048576;
  float* WcT   = (float*)w; w += 1048576;
  float* gi_t  = (float*)w; w += 184320;
  float* h0buf = (float*)w; w += 262144;
  float* Hall  = (float*)w; w += 16777216;
  u16*   Qbf   = (u16*)w;                    // aliased: Pbf reuses after k_scores
  u16*   Pbf   = (u16*)w; w += 8388608;
  float* Sbuf  = (float*)w;                  // aliased over (ctxb | obuf)
  u16*   ctxb  = (u16*)w; w += 8388608;
  float* obuf  = (float*)w; w += 8388608;
  u16*   encb  = (u16*)w; w += 67108864;

  float* out     = (float*)d_out;
  float* out_vec = out;                              // [128][64][30]
  float* out_hT  = out + (size_t)BB*LL*NDICT;        // [1][128][512]
  float* out_att = out_hT + (size_t)BB*HD;           // [128][512][64]

  // prep
  k_interleave_whh<<<G3E, 256, 0, stream>>>(eWhhF, W4F);
  k_interleave_whh<<<G3E, 256, 0, stream>>>(eWhhB, W4B);
  k_transpose<<<(HD*HD+255)/256, 256, 0, stream>>>(Wq, WqT, HD, HD);
  k_transpose<<<(256*1024+255)/256, 256, 0, stream>>>(Wc, WcT, 256, 1024);
  k_prep_whhd<<<(G3D*HD)/256, 256, 0, stream>>>(dWhh, whh_i);
  k_gi_tab<<<dim3(NDICT, 6), 256, 0, stream>>>(emb, dWih, dbih, gi_t);

  // encoder
  k_encoder<<<BB, G3E, 0, stream>>>(x, eWihF, eWihB, W4F, W4B,
                                    ebihF, ebhhF, ebihB, ebhhB, encb, h0buf);

  // decoder recurrence (only sequential part)
  for (int l = 0; l < LL; ++l){
    const float* hprev = (l == 0) ? h0buf : (Hall + (size_t)(l-1)*BB*HD);
    float* hout = Hall + (size_t)l*BB*HD;
    k_hstep<<<256, 256, 0, stream>>>(tgt, gi_t, whh_i, dbhh, hprev, hout, l);
  }

  // batched post-recurrence pipeline
  k_query<<<dim3(128,8), 256, 0, stream>>>(Hall, WqT, bq, Qbf);
  k_scores<<<dim3(128,8), 256, 0, stream>>>(Qbf, encb, Sbuf);
  k_softmax<<<BB*LL, 64, 0, stream>>>(Sbuf, Pbf);
  k_attn_tr<<<dim3(128,8), 256, 0, stream>>>(Pbf, out_att);
  k_ctx<<<dim3(128,8), 256, 0, stream>>>(Pbf, encb, ctxb);
  k_outc<<<dim3(128,4), 256, 0, stream>>>(Hall, ctxb, WcT, bc, obuf);
  k_fc<<<BB, 256, 0, stream>>>(obuf, Wf, bfv, out_vec);
  k_copy<<<(BB*HD+255)/256, 256, 0, stream>>>(Hall + (size_t)63*BB*HD, out_hT, BB*HD);
}

// Round 3
// 1832.708 us; speedup vs baseline: 11.1115x; 2.3791x over previous
//
#include <hip/hip_runtime.h>
#include <hip/hip_bf16.h>

typedef unsigned int u32;
typedef unsigned short u16;
typedef _Float16 f16;
typedef f16 f16x2 __attribute__((ext_vector_type(2)));

#define BB 128
#define TT 512
#define HE 256      // encoder hidden
#define G3E 768
#define HD 512      // decoder hidden (2H)
#define G3D 1536
#define LL 64
#define NDICT 30
#define EMBD 256

__device__ __forceinline__ float sigm(float v){ return 1.f/(1.f + expf(-v)); }
__device__ __forceinline__ u16 f2bf(float f){
  u32 u = __float_as_uint(f);
  u = (u + 0x7FFFu + ((u >> 16) & 1u)) >> 16;
  return (u16)u;
}
__device__ __forceinline__ float bf2f(u16 h){ return __uint_as_float(((u32)h) << 16); }

__device__ __forceinline__ void unp8(uint4 v, float* d){
  d[0]=__uint_as_float((v.x&0xffffu)<<16); d[1]=__uint_as_float(v.x&0xffff0000u);
  d[2]=__uint_as_float((v.y&0xffffu)<<16); d[3]=__uint_as_float(v.y&0xffff0000u);
  d[4]=__uint_as_float((v.z&0xffffu)<<16); d[5]=__uint_as_float(v.z&0xffff0000u);
  d[6]=__uint_as_float((v.w&0xffffu)<<16); d[7]=__uint_as_float(v.w&0xffff0000u);
}

__device__ __forceinline__ ushort4 pk4(float a, float b, float c, float d){
  ushort4 r; r.x=f2bf(a); r.y=f2bf(b); r.z=f2bf(c); r.w=f2bf(d); return r;
}

// dot2: acc += w(2xf16) . h(2xf16), f32 accumulate
__device__ __forceinline__ float dot2f(u32 w, f16x2 h, float acc){
#if __has_builtin(__builtin_amdgcn_fdot2)
  return __builtin_amdgcn_fdot2(__builtin_bit_cast(f16x2, w), h, acc, false);
#else
  f16x2 wv = __builtin_bit_cast(f16x2, w);
  acc = fmaf((float)wv.x, (float)h.x, acc);
  return fmaf((float)wv.y, (float)h.y, acc);
#endif
}

// 16-FMA inner step for the 64x64-tile GEMMs (A_s/B_s are [32][68] k-major)
#define INNER16(Q0,Q1)                                              \
  _Pragma("unroll 8")                                               \
  for (int k = 0; k < 32; ++k){                                     \
    float4 a4 = *(const float4*)&A_s[k*68 + (Q0)*4];                \
    float4 b4 = *(const float4*)&B_s[k*68 + (Q1)*4];                \
    acc[0] =fmaf(a4.x,b4.x,acc[0]);  acc[1] =fmaf(a4.x,b4.y,acc[1]); \
    acc[2] =fmaf(a4.x,b4.z,acc[2]);  acc[3] =fmaf(a4.x,b4.w,acc[3]); \
    acc[4] =fmaf(a4.y,b4.x,acc[4]);  acc[5] =fmaf(a4.y,b4.y,acc[5]); \
    acc[6] =fmaf(a4.y,b4.z,acc[6]);  acc[7] =fmaf(a4.y,b4.w,acc[7]); \
    acc[8] =fmaf(a4.z,b4.x,acc[8]);  acc[9] =fmaf(a4.z,b4.y,acc[9]); \
    acc[10]=fmaf(a4.z,b4.z,acc[10]); acc[11]=fmaf(a4.z,b4.w,acc[11]);\
    acc[12]=fmaf(a4.w,b4.x,acc[12]); acc[13]=fmaf(a4.w,b4.y,acc[13]);\
    acc[14]=fmaf(a4.w,b4.z,acc[14]); acc[15]=fmaf(a4.w,b4.w,acc[15]);\
  }

// ---------- prep: generic transpose  dst[c*R + r] = src[r*C + c] ----------
__global__ __launch_bounds__(256) void k_transpose(const float* __restrict__ src,
                                                   float* __restrict__ dst, int R, int C){
  int idx = blockIdx.x*256 + threadIdx.x;
  if (idx < R*C){
    int r = idx / C, c = idx - r*C;
    dst[(size_t)c*R + r] = src[idx];
  }
}

// ---------- prep: encoder Whh f32 [768][256] x2 dirs -> f16 [2][768][256] ----------
__global__ __launch_bounds__(256) void k_prep_wf16(const float* __restrict__ WF,
                                                   const float* __restrict__ WB,
                                                   u16* __restrict__ dst){
  int idx = blockIdx.x*256 + threadIdx.x;      // 768*256
  dst[idx]          = __builtin_bit_cast(u16, (f16)WF[idx]);
  dst[196608 + idx] = __builtin_bit_cast(u16, (f16)WB[idx]);
}

// ---------- prep: decoder Whh [1536][512] -> [ct 32][kq 128][g 3][c 16][kk 4] ----------
__global__ __launch_bounds__(256) void k_prep_whhd(const float* __restrict__ src,
                                                   float* __restrict__ dst){
  int idx = blockIdx.x*256 + threadIdx.x;      // 1536*512
  int G = idx >> 9, K = idx & 511;
  int g = G >> 9;
  int rem = G & 511;
  int ct = rem >> 4, c = rem & 15;
  int kq = K >> 2, kk = K & 3;
  dst[(size_t)ct*24576 + kq*192 + g*64 + c*4 + kk] = src[idx];
}

// ---------- prep: gi[v][g] = emb[v]@dWih[g] + bih[g] ----------
__global__ __launch_bounds__(256) void k_gi_tab(const float* __restrict__ emb,
                                                const float* __restrict__ Wih,
                                                const float* __restrict__ bih,
                                                float* __restrict__ gi){
  int v = blockIdx.x, gy = blockIdx.y;   // grid (30, 6)
  int g = gy*256 + threadIdx.x;
  __shared__ float e_s[EMBD];
  if (threadIdx.x < EMBD) e_s[threadIdx.x] = emb[(size_t)v*EMBD + threadIdx.x];
  __syncthreads();
  const float4* w4 = (const float4*)(Wih + (size_t)g*EMBD);
  float acc = 0.f;
  #pragma unroll 8
  for (int k = 0; k < EMBD/4; ++k){
    float4 w = w4[k];
    float4 h = *(const float4*)&e_s[k*4];
    acc = fmaf(w.x,h.x,fmaf(w.y,h.y,fmaf(w.z,h.z,fmaf(w.w,h.w,acc))));
  }
  gi[(size_t)v*G3D + g] = acc + bih[g];
}

// ---------- encoder: one block per (batch, direction); weights in VGPRs ----------
// 768 threads: thread j owns Whh row j (256 f16 = 128 VGPRs).
// h lives in LDS as f16; all lanes read the same h[k] -> broadcast ds_read.
__global__ __launch_bounds__(768, 3) void k_enc_p(
    const float* __restrict__ x,
    const u16* __restrict__ Wp,                 // [2][768][256] f16 bits
    const float* __restrict__ WihF, const float* __restrict__ WihB,
    const float* __restrict__ bihF, const float* __restrict__ bhhF,
    const float* __restrict__ bihB, const float* __restrict__ bhhB,
    u16* __restrict__ enc_out, float* __restrict__ h0out)
{
  const int b   = blockIdx.x >> 1;
  const int dir = blockIdx.x & 1;
  const int j   = threadIdx.x;
  const float* Wih = dir ? WihB : WihF;
  const float* bih = dir ? bihB : bihF;
  const float* bhh = dir ? bhhB : bhhF;

  __shared__ __align__(16) f16 h_lds[HE];   // 512 B
  __shared__ float gh[G3E];                 // 3 KB
  __shared__ float wv0[G3E], wv1[G3E], bis[G3E], bhs[G3E];  // 12 KB

  // Whh row j -> registers (128 VGPRs as u32 pairs of f16)
  u32 w[128];
  {
    const uint4* wsrc = (const uint4*)(Wp + ((size_t)dir*G3E + j)*HE);
    #pragma unroll
    for (int i = 0; i < 32; ++i){
      uint4 v = wsrc[i];
      w[i*4+0]=v.x; w[i*4+1]=v.y; w[i*4+2]=v.z; w[i*4+3]=v.w;
    }
  }
  wv0[j] = Wih[j*2+0]; wv1[j] = Wih[j*2+1];
  bis[j] = bih[j];     bhs[j] = bhh[j];
  if (j < HE) h_lds[j] = (f16)0.f;
  float h_own = 0.f;                        // thread j<256 carries h[j] in f32
  __syncthreads();

  for (int t = 0; t < TT; ++t){
    const int tt = dir ? (TT-1-t) : t;
    // gh[j] = Whh[j,:] . h  (f16 dot2, f32 accumulate; h reads are broadcast)
    float acc = 0.f;
    #pragma unroll
    for (int kq = 0; kq < 64; ++kq){
      f16x2 h0 = *(const f16x2*)&h_lds[kq*4];
      f16x2 h1 = *(const f16x2*)&h_lds[kq*4+2];
      acc = dot2f(w[kq*2+0], h0, acc);
      acc = dot2f(w[kq*2+1], h1, acc);
    }
    gh[j] = acc;
    __syncthreads();
    if (j < HE){
      const float x0 = x[((size_t)b*TT + tt)*2 + 0];
      const float x1 = x[((size_t)b*TT + tt)*2 + 1];
      float gr = wv0[j]*x0 + wv1[j]*x1 + bis[j] + gh[j] + bhs[j];
      float gz = wv0[j+HE]*x0 + wv1[j+HE]*x1 + bis[j+HE] + gh[j+HE] + bhs[j+HE];
      float r = sigm(gr), z = sigm(gz);
      float gin = wv0[j+2*HE]*x0 + wv1[j+2*HE]*x1 + bis[j+2*HE];
      float n = tanhf(gin + r*(gh[j+2*HE] + bhs[j+2*HE]));
      float hnew = (1.f - z)*n + z*h_own;
      h_own = hnew;
      h_lds[j] = (f16)hnew;
      enc_out[((size_t)b*TT + tt)*HD + dir*HE + j] = f2bf(hnew);
    }
    __syncthreads();
  }
  if (j < HE) h0out[(size_t)b*HD + dir*HE + j] = h_own;
}

// ---------- decoder recurrence: one step, gh = h@Whh^T, gates, h_new ----------
__global__ __launch_bounds__(256) void k_hstep(
    const int* __restrict__ tgt, const float* __restrict__ gi_tab,
    const float* __restrict__ whh_i, const float* __restrict__ bhh,
    const float* __restrict__ hprev, float* __restrict__ hout, int l)
{
  const int bt = blockIdx.x & 7, ct = blockIdx.x >> 3;
  const int tid = threadIdx.x;
  const int b = tid & 15, c = tid >> 4;
  __shared__ float h_s[16*516];
  __shared__ float wtile[32*192];
  __shared__ int tok_s[16];

  {
    const int bs = tid >> 4, seg = tid & 15;
    const float4* src = (const float4*)(hprev + (size_t)(bt*16+bs)*HD + seg*32);
    float4* dst = (float4*)&h_s[bs*516 + seg*32];
    #pragma unroll
    for (int r = 0; r < 8; ++r) dst[r] = src[r];
  }
  if (tid < 16) tok_s[tid] = (l == 0) ? 1 : tgt[(size_t)(bt*16+tid)*LL + (l-1)];

  float gr = 0.f, gz = 0.f, gn = 0.f;
  const float* wbase = whh_i + (size_t)ct*24576;
  for (int kc = 0; kc < 4; ++kc){
    __syncthreads();
    {
      const float4* src = (const float4*)(wbase + kc*6144);
      float4* dst = (float4*)wtile;
      #pragma unroll
      for (int i = 0; i < 6; ++i) dst[tid + i*256] = src[tid + i*256];
    }
    __syncthreads();
    #pragma unroll 8
    for (int kq = 0; kq < 32; ++kq){
      float4 h4 = *(const float4*)&h_s[b*516 + kc*128 + kq*4];
      float4 w0 = *(const float4*)&wtile[kq*192 +       c*4];
      float4 w1 = *(const float4*)&wtile[kq*192 + 64  + c*4];
      float4 w2 = *(const float4*)&wtile[kq*192 + 128 + c*4];
      gr = fmaf(w0.x,h4.x,fmaf(w0.y,h4.y,fmaf(w0.z,h4.z,fmaf(w0.w,h4.w,gr))));
      gz = fmaf(w1.x,h4.x,fmaf(w1.y,h4.y,fmaf(w1.z,h4.z,fmaf(w1.w,h4.w,gz))));
      gn = fmaf(w2.x,h4.x,fmaf(w2.y,h4.y,fmaf(w2.z,h4.z,fmaf(w2.w,h4.w,gn))));
    }
  }
  const int C = ct*16 + c;
  const int tok = tok_s[b];
  float gir = gi_tab[(size_t)tok*G3D + C];
  float giz = gi_tab[(size_t)tok*G3D + HD + C];
  float gin = gi_tab[(size_t)tok*G3D + 2*HD + C];
  float r = sigm(gir + gr + bhh[C]);
  float z = sigm(giz + gz + bhh[HD + C]);
  float n = tanhf(gin + r*(gn + bhh[2*HD + C]));
  float hp = h_s[b*516 + C];
  hout[(size_t)(bt*16+b)*HD + C] = (1.f - z)*n + z*hp;
}

// ---------- Q = Hall @ WqT + bq -> bf16 ; grid (128 rt, 8 nt) ----------
__global__ __launch_bounds__(256) void k_query(const float* __restrict__ Hall,
                                               const float* __restrict__ WqT,
                                               const float* __restrict__ bq,
                                               u16* __restrict__ Qbf){
  const int rt = blockIdx.x, nt = blockIdx.y;
  const int tid = threadIdx.x;
  __shared__ float A_s[32*68];
  __shared__ float B_s[32*68];
  const int rq = tid >> 4, nq = tid & 15;
  const int i = tid >> 2, jj = tid & 3;
  const int i2 = tid >> 3, jj2 = tid & 7;
  float acc[16] = {};
  for (int kc = 0; kc < 16; ++kc){
    __syncthreads();
    {
      const float* src = Hall + (size_t)(rt*64 + i)*HD + kc*32 + jj*8;
      float4 v0 = *(const float4*)src, v1 = *(const float4*)(src+4);
      A_s[(jj*8+0)*68+i]=v0.x; A_s[(jj*8+1)*68+i]=v0.y;
      A_s[(jj*8+2)*68+i]=v0.z; A_s[(jj*8+3)*68+i]=v0.w;
      A_s[(jj*8+4)*68+i]=v1.x; A_s[(jj*8+5)*68+i]=v1.y;
      A_s[(jj*8+6)*68+i]=v1.z; A_s[(jj*8+7)*68+i]=v1.w;
    }
    {
      const float* src = WqT + (size_t)(kc*32 + i2)*HD + nt*64 + jj2*8;
      *(float4*)&B_s[i2*68 + jj2*8]     = *(const float4*)src;
      *(float4*)&B_s[i2*68 + jj2*8 + 4] = *(const float4*)(src+4);
    }
    __syncthreads();
    INNER16(rq, nq)
  }
  const int n0 = nt*64 + nq*4;
  float4 bv = *(const float4*)&bq[n0];
  #pragma unroll
  for (int r = 0; r < 4; ++r){
    u16* dst = Qbf + (size_t)(rt*64 + rq*4 + r)*HD + n0;
    *(ushort4*)dst = pk4(acc[r*4+0]+bv.x, acc[r*4+1]+bv.y,
                         acc[r*4+2]+bv.z, acc[r*4+3]+bv.w);
  }
}

// ---------- S[b][l][t] = Q[b,l,:] . enc[b,t,:] ; grid (128 b, 8 tt) ----------
__global__ __launch_bounds__(256) void k_scores(const u16* __restrict__ Qbf,
                                                const u16* __restrict__ enc,
                                                float* __restrict__ Sbuf){
  const int bI = blockIdx.x, tt = blockIdx.y;
  const int tid = threadIdx.x;
  __shared__ float A_s[32*68];
  __shared__ float B_s[32*68];
  const int lq = tid >> 4, tq = tid & 15;
  const int i = tid >> 2, jj = tid & 3;
  float acc[16] = {};
  for (int kc = 0; kc < 16; ++kc){
    __syncthreads();
    float tmp[8];
    {
      uint4 va = *(const uint4*)(Qbf + ((size_t)i*BB + bI)*HD + kc*32 + jj*8);
      unp8(va, tmp);
      #pragma unroll
      for (int m = 0; m < 8; ++m) A_s[(jj*8+m)*68 + i] = tmp[m];
    }
    {
      uint4 vb = *(const uint4*)(enc + ((size_t)bI*TT + tt*64 + i)*HD + kc*32 + jj*8);
      unp8(vb, tmp);
      #pragma unroll
      for (int m = 0; m < 8; ++m) B_s[(jj*8+m)*68 + i] = tmp[m];
    }
    __syncthreads();
    INNER16(lq, tq)
  }
  #pragma unroll
  for (int r = 0; r < 4; ++r){
    float4 o = make_float4(acc[r*4+0],acc[r*4+1],acc[r*4+2],acc[r*4+3]);
    *(float4*)&Sbuf[((size_t)bI*LL + lq*4+r)*TT + tt*64 + tq*4] = o;
  }
}

// ---------- row softmax over t: P bf16 ; grid 8192 x 64 ----------
__global__ __launch_bounds__(64) void k_softmax(const float* __restrict__ Sbuf,
                                                u16* __restrict__ Pbf){
  const int row = blockIdx.x;
  const int lane = threadIdx.x;
  const float* s = Sbuf + (size_t)row*TT;
  float v[8]; float m = -1e30f;
  #pragma unroll
  for (int i = 0; i < 8; ++i){ v[i] = s[lane + i*64]; m = fmaxf(m, v[i]); }
  #pragma unroll
  for (int o = 32; o; o >>= 1) m = fmaxf(m, __shfl_xor(m, o));
  float Z = 0.f;
  #pragma unroll
  for (int i = 0; i < 8; ++i){ v[i] = expf(v[i] - m); Z += v[i]; }
  #pragma unroll
  for (int o = 32; o; o >>= 1) Z += __shfl_xor(Z, o);
  float inv = 1.f / Z;
  u16* p = Pbf + (size_t)row*TT;
  #pragma unroll
  for (int i = 0; i < 8; ++i) p[lane + i*64] = f2bf(v[i]*inv);
}

// ---------- attn[b][t][l] = f32(P[b][l][t]) ; grid (128 b, 8 tt) ----------
__global__ __launch_bounds__(256) void k_attn_tr(const u16* __restrict__ Pbf,
                                                 float* __restrict__ att){
  const int bI = blockIdx.x, tt = blockIdx.y;
  const int tid = threadIdx.x;
  __shared__ u16 tile[64][72];
  {
    const int i = tid >> 2, jj = tid & 3;
    #pragma unroll
    for (int rep = 0; rep < 2; ++rep){
      int ch = jj + rep*4;
      uint4 v = *(const uint4*)(Pbf + ((size_t)bI*LL + i)*TT + tt*64 + ch*8);
      *(uint4*)&tile[i][ch*8] = v;
    }
  }
  __syncthreads();
  const int t = tid >> 2, jl = tid & 3;
  #pragma unroll
  for (int rep = 0; rep < 4; ++rep){
    int l0 = jl*16 + rep*4;
    float4 o;
    o.x = bf2f(tile[l0+0][t]); o.y = bf2f(tile[l0+1][t]);
    o.z = bf2f(tile[l0+2][t]); o.w = bf2f(tile[l0+3][t]);
    *(float4*)&att[((size_t)bI*TT + tt*64 + t)*LL + l0] = o;
  }
}

// ---------- ctx[l*128+b][n] = P[b,l,:] @ enc[b,:,n] -> bf16 ; grid (128 b, 8 nt) ----------
__global__ __launch_bounds__(256) void k_ctx(const u16* __restrict__ Pbf,
                                             const u16* __restrict__ enc,
                                             u16* __restrict__ ctxb){
  const int bI = blockIdx.x, nt = blockIdx.y;
  const int tid = threadIdx.x;
  __shared__ float A_s[32*68];
  __shared__ float B_s[32*68];
  const int lq = tid >> 4, nq = tid & 15;
  const int i = tid >> 2, jj = tid & 3;
  const int i2 = tid >> 3, jj2 = tid & 7;
  float acc[16] = {};
  for (int tc = 0; tc < 16; ++tc){
    __syncthreads();
    {
      float tmp[8];
      uint4 va = *(const uint4*)(Pbf + ((size_t)bI*LL + i)*TT + tc*32 + jj*8);
      unp8(va, tmp);
      #pragma unroll
      for (int m = 0; m < 8; ++m) A_s[(jj*8+m)*68 + i] = tmp[m];
    }
    {
      float tmp[8];
      uint4 vb = *(const uint4*)(enc + ((size_t)bI*TT + tc*32 + i2)*HD + nt*64 + jj2*8);
      unp8(vb, tmp);
      *(float4*)&B_s[i2*68 + jj2*8]     = make_float4(tmp[0],tmp[1],tmp[2],tmp[3]);
      *(float4*)&B_s[i2*68 + jj2*8 + 4] = make_float4(tmp[4],tmp[5],tmp[6],tmp[7]);
    }
    __syncthreads();
    INNER16(lq, nq)
  }
  const int n0 = nt*64 + nq*4;
  #pragma unroll
  for (int r = 0; r < 4; ++r){
    int ll = lq*4 + r;
    u16* dst = ctxb + ((size_t)ll*BB + bI)*HD + n0;
    *(ushort4*)dst = pk4(acc[r*4+0], acc[r*4+1], acc[r*4+2], acc[r*4+3]);
  }
}

// ---------- o = [Hall|ctx] @ WcT + bc ; grid (128 rt, 4 nt) ----------
__global__ __launch_bounds__(256) void k_outc(const float* __restrict__ Hall,
                                              const u16* __restrict__ ctxb,
                                              const float* __restrict__ WcT,
                                              const float* __restrict__ bc,
                                              float* __restrict__ obuf){
  const int rt = blockIdx.x, nt = blockIdx.y;
  const int tid = threadIdx.x;
  __shared__ float A_s[32*68];
  __shared__ float B_s[32*68];
  const int rq = tid >> 4, nq = tid & 15;
  const int i = tid >> 2, jj = tid & 3;
  const int i2 = tid >> 3, jj2 = tid & 7;
  float acc[16] = {};
  for (int kc = 0; kc < 32; ++kc){
    __syncthreads();
    if (kc < 16){
      const float* src = Hall + (size_t)(rt*64 + i)*HD + kc*32 + jj*8;
      float4 v0 = *(const float4*)src, v1 = *(const float4*)(src+4);
      A_s[(jj*8+0)*68+i]=v0.x; A_s[(jj*8+1)*68+i]=v0.y;
      A_s[(jj*8+2)*68+i]=v0.z; A_s[(jj*8+3)*68+i]=v0.w;
      A_s[(jj*8+4)*68+i]=v1.x; A_s[(jj*8+5)*68+i]=v1.y;
      A_s[(jj*8+6)*68+i]=v1.z; A_s[(jj*8+7)*68+i]=v1.w;
    } else {
      float tmp[8];
      uint4 v = *(const uint4*)(ctxb + (size_t)(rt*64 + i)*HD + (kc-16)*32 + jj*8);
      unp8(v, tmp);
      #pragma unroll
      for (int m = 0; m < 8; ++m) A_s[(jj*8+m)*68 + i] = tmp[m];
    }
    {
      const float* src = WcT + (size_t)(kc*32 + i2)*256 + nt*64 + jj2*8;
      *(float4*)&B_s[i2*68 + jj2*8]     = *(const float4*)src;
      *(float4*)&B_s[i2*68 + jj2*8 + 4] = *(const float4*)(src+4);
    }
    __syncthreads();
    INNER16(rq, nq)
  }
  const int n0 = nt*64 + nq*4;
  float4 bv = *(const float4*)&bc[n0];
  #pragma unroll
  for (int r = 0; r < 4; ++r){
    float4 o = make_float4(acc[r*4+0]+bv.x, acc[r*4+1]+bv.y,
                           acc[r*4+2]+bv.z, acc[r*4+3]+bv.w);
    *(float4*)&obuf[(size_t)(rt*64 + rq*4 + r)*256 + n0] = o;
  }
}

// ---------- logits = o @ Wf^T + bf ; grid 128 ----------
__global__ __launch_bounds__(256) void k_fc(const float* __restrict__ obuf,
                                            const float* __restrict__ Wf,
                                            const float* __restrict__ bfv,
                                            float* __restrict__ out_vec){
  const int rt = blockIdx.x;
  const int tid = threadIdx.x;
  __shared__ float w_s[30*260];
  for (int rr = 0; rr < 30; ++rr) w_s[rr*260 + tid] = Wf[(size_t)rr*256 + tid];
  __syncthreads();
  const int rl = tid >> 2, dq = tid & 3;
  const int r = rt*64 + rl;
  float acc[8] = {};
  for (int k = 0; k < 256; k += 4){
    float4 o4 = *(const float4*)&obuf[(size_t)r*256 + k];
    #pragma unroll
    for (int jq = 0; jq < 8; ++jq){
      int d = dq*8 + jq;
      if (d < 30){
        float4 w4 = *(const float4*)&w_s[d*260 + k];
        acc[jq] = fmaf(o4.x,w4.x,fmaf(o4.y,w4.y,fmaf(o4.z,w4.z,fmaf(o4.w,w4.w,acc[jq]))));
      }
    }
  }
  const int b = r & 127, l = r >> 7;
  #pragma unroll
  for (int jq = 0; jq < 8; ++jq){
    int d = dq*8 + jq;
    if (d < 30) out_vec[((size_t)b*LL + l)*NDICT + d] = acc[jq] + bfv[d];
  }
}

__global__ __launch_bounds__(256) void k_copy(const float* __restrict__ src,
                                              float* __restrict__ dst, int n){
  int i = blockIdx.x*256 + threadIdx.x;
  if (i < n) dst[i] = src[i];
}

extern "C" void kernel_launch(void* const* d_in, const int* in_sizes, int n_in,
                              void* d_out, int out_size, void* d_ws, size_t ws_size,
                              hipStream_t stream)
{
  const float* x     = (const float*)d_in[0];
  const int*   tgt   = (const int*)  d_in[1];
  const float* eWihF = (const float*)d_in[2];
  const float* eWhhF = (const float*)d_in[3];
  const float* ebihF = (const float*)d_in[4];
  const float* ebhhF = (const float*)d_in[5];
  const float* eWihB = (const float*)d_in[6];
  const float* eWhhB = (const float*)d_in[7];
  const float* ebihB = (const float*)d_in[8];
  const float* ebhhB = (const float*)d_in[9];
  const float* emb   = (const float*)d_in[10];
  const float* dWih  = (const float*)d_in[11];
  const float* dWhh  = (const float*)d_in[12];
  const float* dbih  = (const float*)d_in[13];
  const float* dbhh  = (const float*)d_in[14];
  const float* Wq    = (const float*)d_in[15];
  const float* bq    = (const float*)d_in[16];
  const float* Wc    = (const float*)d_in[17];
  const float* bc    = (const float*)d_in[18];
  const float* Wf    = (const float*)d_in[19];
  const float* bfv   = (const float*)d_in[20];

  char* w = (char*)d_ws;
  u16*   Wpf16 = (u16*)w;  w += 786432;      // [2][768][256] f16
  float* whh_i = (float*)w; w += 3145728;
  float* WqT   = (float*)w; w += 1048576;
  float* WcT   = (float*)w; w += 1048576;
  float* gi_t  = (float*)w; w += 184320;
  float* h0buf = (float*)w; w += 262144;
  float* Hall  = (float*)w; w += 16777216;
  u16*   Qbf   = (u16*)w;                    // aliased: Pbf reuses after k_scores
  u16*   Pbf   = (u16*)w; w += 8388608;
  float* Sbuf  = (float*)w;                  // aliased over (ctxb | obuf)
  u16*   ctxb  = (u16*)w; w += 8388608;
  float* obuf  = (float*)w; w += 8388608;
  u16*   encb  = (u16*)w; w += 67108864;

  float* out     = (float*)d_out;
  float* out_vec = out;                              // [128][64][30]
  float* out_hT  = out + (size_t)BB*LL*NDICT;        // [1][128][512]
  float* out_att = out_hT + (size_t)BB*HD;           // [128][512][64]

  // prep
  k_prep_wf16<<<G3E, 256, 0, stream>>>(eWhhF, eWhhB, Wpf16);
  k_transpose<<<(HD*HD+255)/256, 256, 0, stream>>>(Wq, WqT, HD, HD);
  k_transpose<<<(256*1024+255)/256, 256, 0, stream>>>(Wc, WcT, 256, 1024);
  k_prep_whhd<<<(G3D*HD)/256, 256, 0, stream>>>(dWhh, whh_i);
  k_gi_tab<<<dim3(NDICT, 6), 256, 0, stream>>>(emb, dWih, dbih, gi_t);

  // encoder: 256 independent recurrences, weights register-resident
  k_enc_p<<<BB*2, G3E, 0, stream>>>(x, Wpf16, eWihF, eWihB,
                                    ebihF, ebhhF, ebihB, ebhhB, encb, h0buf);

  // decoder recurrence (only sequential part)
  for (int l = 0; l < LL; ++l){
    const float* hprev = (l == 0) ? h0buf : (Hall + (size_t)(l-1)*BB*HD);
    float* hout = Hall + (size_t)l*BB*HD;
    k_hstep<<<256, 256, 0, stream>>>(tgt, gi_t, whh_i, dbhh, hprev, hout, l);
  }

  // batched post-recurrence pipeline
  k_query<<<dim3(128,8), 256, 0, stream>>>(Hall, WqT, bq, Qbf);
  k_scores<<<dim3(128,8), 256, 0, stream>>>(Qbf, encb, Sbuf);
  k_softmax<<<BB*LL, 64, 0, stream>>>(Sbuf, Pbf);
  k_attn_tr<<<dim3(128,8), 256, 0, stream>>>(Pbf, out_att);
  k_ctx<<<dim3(128,8), 256, 0, stream>>>(Pbf, encb, ctxb);
  k_outc<<<dim3(128,4), 256, 0, stream>>>(Hall, ctxb, WcT, bc, obuf);
  k_fc<<<BB, 256, 0, stream>>>(obuf, Wf, bfv, out_vec);
  k_copy<<<(BB*HD+255)/256, 256, 0, stream>>>(Hall + (size_t)63*BB*HD, out_hT, BB*HD);
}